// Round 8
// baseline (257.861 us; speedup 1.0000x reference)
//
#include <hip/hip_runtime.h>
#include <hip/hip_bf16.h>
#include <stdint.h>

// Problem constants (fixed by the reference setup_inputs)
#define BATCH  16384
#define D_IN   1024
#define M_HID  4096
#define R_LORA 16
#define SCALING 2.0f   // ALPHA/R = 32/16

// R8 == R7 with the nontemporal-load type fixed (native ext_vector float4).
// R7 theory: 690 cyc/iter-pair vs 256 MFMA; changes: (1) af dist-1 register
// prefetch; (2) wf rotation depth 8 with cross-pass continuous refill; (3)
// nontemporal x/W0 loads (read-once data) to protect wb L2 residency.
#define STRIP    64
#define NTHREADS 512

typedef __bf16 bf16x8 __attribute__((ext_vector_type(8)));
typedef float  f32x16 __attribute__((ext_vector_type(16)));
typedef float  nfloat4 __attribute__((ext_vector_type(4)));   // builtin-compatible

__device__ __forceinline__ unsigned short f2bf(float f) {
    union { float f; unsigned int u; } c; c.f = f;
    unsigned int u = c.u;
    return (unsigned short)((u + 0x7FFFu + ((u >> 16) & 1u)) >> 16);
}

// ---------------- prep: W_eff -> fragment-ordered bf16 (coalesced) ----------------
// Layout (consumed by k_strip): short-offset n32*32768 + c*256 + rl*8 + j
// holds W_eff[n32*32 + rl][c*8 + j],  c in [0,128), rl in [0,32), j in [0,8).
__global__ __launch_bounds__(256) void k_wprep(
    const float* __restrict__ W0, const float* __restrict__ A,
    const float* __restrict__ Bl, unsigned short* __restrict__ wb)
{
    __shared__ unsigned short T[32][D_IN + 8];
    const int n32 = blockIdx.x;                   // 128 blocks
    const int t   = threadIdx.x;                  // 256 threads

    nfloat4 Areg[R_LORA];
#pragma unroll
    for (int j = 0; j < R_LORA; ++j)
        Areg[j] = *(const nfloat4*)(A + j * D_IN + t * 4);

#pragma unroll 4
    for (int r = 0; r < 32; ++r) {
        const int n = n32 * 32 + r;
        nfloat4 v = __builtin_nontemporal_load(
            (const nfloat4*)(W0 + (size_t)n * D_IN + t * 4));
        const float* brow = Bl + n * R_LORA;
#pragma unroll
        for (int j = 0; j < R_LORA; ++j) {
            float s = SCALING * brow[j];
            v = v + s * Areg[j];
        }
        ushort4 o = make_ushort4(f2bf(v[0]), f2bf(v[1]), f2bf(v[2]), f2bf(v[3]));
        *(ushort4*)(&T[r][t * 4]) = o;
    }
    __syncthreads();

    unsigned short* dst = wb + (size_t)n32 * 32768;
#pragma unroll
    for (int i = 0; i < 16; ++i) {
        int L  = t * 128 + i * 8;
        int c  = L >> 8;
        int rl = (L >> 3) & 31;
        uint4 v = *(const uint4*)(&T[rl][c * 8]);
        *(uint4*)(dst + L) = v;
    }
}

// ---------------- main fused kernel ----------------
__global__ __launch_bounds__(NTHREADS, 2) void k_strip(
    const float* __restrict__ xf, const unsigned short* __restrict__ wb,
    const float* __restrict__ b0, const float* __restrict__ W2,
    const float* __restrict__ b2, float* __restrict__ out)
{
    // x strip, chunk-major: As[c*512 + r*8 + j] = x_bf16[row0+r][c*8+j]
    __shared__ unsigned short As[STRIP * D_IN];   // 128 KiB
    __shared__ float red[8][STRIP];               // 2 KiB cross-wave reduce

    const int tid  = threadIdx.x;
    const int lane = tid & 63;
    const int wave = tid >> 6;
    const int rl   = lane & 31;
    const int half = lane >> 5;
    const int row0 = blockIdx.x * STRIP;

    // ---- phase 1: x fp32 -> bf16 into resident LDS strip (nontemporal:
    //      each x line is read exactly once globally; keep L2 for wb) ----
    {
        const int r  = tid >> 3;                  // 0..63
        const int c0 = tid & 7;
        const float* xr = xf + (size_t)(row0 + r) * D_IN;
#pragma unroll
        for (int i = 0; i < 16; ++i) {
            int c = i * 8 + c0;
            nfloat4 v0 = __builtin_nontemporal_load((const nfloat4*)(xr + c * 8));
            nfloat4 v1 = __builtin_nontemporal_load((const nfloat4*)(xr + c * 8 + 4));
            uint4 o;
            o.x = (unsigned)f2bf(v0[0]) | ((unsigned)f2bf(v0[1]) << 16);
            o.y = (unsigned)f2bf(v0[2]) | ((unsigned)f2bf(v0[3]) << 16);
            o.z = (unsigned)f2bf(v1[0]) | ((unsigned)f2bf(v1[1]) << 16);
            o.w = (unsigned)f2bf(v1[2]) | ((unsigned)f2bf(v1[3]) << 16);
            *(uint4*)(&As[c * 512 + r * 8]) = o;
        }
    }
    __syncthreads();   // the only barrier before the final reduce

    float rowpart[2][16];
#pragma unroll
    for (int ti = 0; ti < 2; ++ti)
#pragma unroll
        for (int r = 0; r < 16; ++r) rowpart[ti][r] = 0.f;

    // W stream base for this wave (pass stride = 16*32768 shorts = 1 MiB)
    const unsigned short* w0base = wb + (size_t)(wave * 2) * 32768 + half * 256 + rl * 8;

    // depth-8 rotating prefetch, continuously refilled across passes
    bf16x8 wf0[8], wf1[8];
#pragma unroll
    for (int p = 0; p < 8; ++p) {
        wf0[p] = *(const bf16x8*)(w0base + p * 512);
        wf1[p] = *(const bf16x8*)(w0base + 32768 + p * 512);
    }

    // af current fragments (kk=0); prefetched distance-1 inside the loop
    const int abase = half * 512 + rl * 8;
    bf16x8 a0 = *(const bf16x8*)(&As[abase]);
    bf16x8 a1 = *(const bf16x8*)(&As[abase + 256]);

    for (int pass = 0; pass < 8; ++pass) {
        const int n0 = wave * 64 + pass * 512;
        const float w2a = W2[n0 + rl],      b0a = b0[n0 + rl];
        const float w2b = W2[n0 + 32 + rl], b0b = b0[n0 + 32 + rl];
        const unsigned short* wp  = w0base + (size_t)pass * 524288;
        // pass 7: "next" re-reads pass 7 (L1/L2-hot, dead slots) -> no OOB
        const unsigned short* wpn = wp + (pass < 7 ? 524288 : 0);

        f32x16 acc[2][2] = {};

#pragma unroll 8
        for (int kk = 0; kk < 64; ++kk) {
            const int cur = kk & 7;
            bf16x8 w0c = wf0[cur], w1c = wf1[cur];
            // af distance-1 prefetch (pass-independent; wraps to kk=0 for next pass)
            const int nkk = (kk + 1) & 63;
            const int noff = (nkk * 2 + half) * 512 + rl * 8;
            bf16x8 a0n = *(const bf16x8*)(&As[noff]);
            bf16x8 a1n = *(const bf16x8*)(&As[noff + 256]);
            // wf refill: chunk kk+8 of this pass, or chunk kk-56 of next pass
            if (kk < 56) {
                wf0[cur] = *(const bf16x8*)(wp + (kk + 8) * 512);
                wf1[cur] = *(const bf16x8*)(wp + 32768 + (kk + 8) * 512);
            } else {
                wf0[cur] = *(const bf16x8*)(wpn + (kk - 56) * 512);
                wf1[cur] = *(const bf16x8*)(wpn + 32768 + (kk - 56) * 512);
            }
            acc[0][0] = __builtin_amdgcn_mfma_f32_32x32x16_bf16(a0, w0c, acc[0][0], 0, 0, 0);
            acc[0][1] = __builtin_amdgcn_mfma_f32_32x32x16_bf16(a0, w1c, acc[0][1], 0, 0, 0);
            acc[1][0] = __builtin_amdgcn_mfma_f32_32x32x16_bf16(a1, w0c, acc[1][0], 0, 0, 0);
            acc[1][1] = __builtin_amdgcn_mfma_f32_32x32x16_bf16(a1, w1c, acc[1][1], 0, 0, 0);
            a0 = a0n; a1 = a1n;
        }

        // fold this pass: relu(h + bias) dot W2, accumulate per-lane
#pragma unroll
        for (int ti = 0; ti < 2; ++ti)
#pragma unroll
            for (int r = 0; r < 16; ++r)
                rowpart[ti][r] += fmaxf(acc[ti][0][r] + b0a, 0.f) * w2a
                                + fmaxf(acc[ti][1][r] + b0b, 0.f) * w2b;
    }

    // ---- final: shuffle-reduce over 32 col-lanes, cross-wave sum via LDS ----
    // C/D layout (m74/m101): col = lane&31, row = (r&3) + 8*(r>>2) + 4*half
#pragma unroll
    for (int ti = 0; ti < 2; ++ti)
#pragma unroll
        for (int r = 0; r < 16; ++r) {
            float p = rowpart[ti][r];
#pragma unroll
            for (int m = 1; m <= 16; m <<= 1)
                p += __shfl_xor(p, m, 64);        // stays within each 32-half
            if (rl == 0)
                red[wave][ti * 32 + (r & 3) + 8 * (r >> 2) + 4 * half] = p;
        }
    __syncthreads();
    if (tid < STRIP) {
        float s = b2[0];
#pragma unroll
        for (int w = 0; w < 8; ++w) s += red[w][tid];
        out[row0 + tid] = s;
    }
}

// ---------------- naive fallback (correctness only; ws too small) ----------------
__global__ __launch_bounds__(256) void k_naive(
    const float* __restrict__ x, const float* __restrict__ W0,
    const float* __restrict__ b0, const float* __restrict__ A,
    const float* __restrict__ Bl, const float* __restrict__ W2,
    const float* __restrict__ b2, float* __restrict__ out)
{
    __shared__ float xs[D_IN];
    int b = blockIdx.x;
    for (int d = threadIdx.x; d < D_IN; d += 256) xs[d] = x[(size_t)b * D_IN + d];
    __syncthreads();
    float part = 0.f;
    for (int m = threadIdx.x; m < M_HID; m += 256) {
        float h = b0[m];
        const float* wr = W0 + (size_t)m * D_IN;
        const float* brow = Bl + m * R_LORA;
        for (int d = 0; d < D_IN; ++d) {
            float w = wr[d];
            for (int r = 0; r < R_LORA; ++r) w += SCALING * brow[r] * A[r * D_IN + d];
            h += xs[d] * w;
        }
        part += fmaxf(h, 0.f) * W2[m];
    }
    __shared__ float sred[256];
    sred[threadIdx.x] = part;
    __syncthreads();
    for (int s = 128; s > 0; s >>= 1) {
        if (threadIdx.x < s) sred[threadIdx.x] += sred[threadIdx.x + s];
        __syncthreads();
    }
    if (threadIdx.x == 0) out[b] = sred[0] + b2[0];
}

// ---------------- host ----------------
extern "C" void kernel_launch(void* const* d_in, const int* in_sizes, int n_in,
                              void* d_out, int out_size, void* d_ws, size_t ws_size,
                              hipStream_t stream) {
    const float* x  = (const float*)d_in[0];
    const float* W0 = (const float*)d_in[1];
    const float* b0 = (const float*)d_in[2];
    const float* A  = (const float*)d_in[3];
    const float* Bl = (const float*)d_in[4];
    const float* W2 = (const float*)d_in[5];
    const float* b2 = (const float*)d_in[6];
    float* out = (float*)d_out;

    const size_t wb_bytes = (size_t)M_HID * D_IN * 2;   // 8 MiB fragment-ordered W_eff
    if (ws_size >= wb_bytes) {
        unsigned short* wb = (unsigned short*)d_ws;
        hipLaunchKernelGGL(k_wprep, dim3(M_HID / 32), dim3(256), 0, stream,
                           W0, A, Bl, wb);
        hipLaunchKernelGGL(k_strip, dim3(BATCH / STRIP), dim3(NTHREADS), 0, stream,
                           x, wb, b0, W2, b2, out);
    } else {
        hipLaunchKernelGGL(k_naive, dim3(BATCH), dim3(256), 0, stream,
                           x, W0, b0, A, Bl, W2, b2, out);
    }
}